// Round 1
// 663.029 us; speedup vs baseline: 1.2562x; 1.2562x over previous
//
#include <hip/hip_runtime.h>
#include <hip/hip_bf16.h>

#define NB 64
#define ND 1500
#define NT 1000
#define NA 512
#define KSTEPS 47   // ceil(1500/32)
#define STR 17      // Bs t-stride in dwords (16 k-pair dwords + 1 pad)

typedef __bf16 bf16x8 __attribute__((ext_vector_type(8)));
typedef float  f32x4  __attribute__((ext_vector_type(4)));

union BQ { unsigned u[4]; bf16x8 v; };

static __device__ __forceinline__ unsigned pack2(float lo, float hi) {
    __bf16 l = (__bf16)lo, h = (__bf16)hi;
    unsigned short lu = __builtin_bit_cast(unsigned short, l);
    unsigned short hu = __builtin_bit_cast(unsigned short, h);
    return ((unsigned)hu << 16) | (unsigned)lu;
}

// ---------------- kernel 0: pack w1 [D,NA] fp32 -> MFMA-fragment-ordered bf16 ----------------
// Layout: elem offset = ((ks*32 + a16)*64 + lane)*8, lane=(quad<<4)|col holds
// A[a = a16*16+col][k = ks*32 + quad*8 + j], j=0..7 (zero-padded for d >= ND).
// Score kernel's per-lane 16B A-frag loads are then fully coalesced (lane-consecutive).
__global__ void w1p_kernel(const float* __restrict__ w1, __bf16* __restrict__ w1p) {
    int g = blockIdx.x * 256 + threadIdx.x;       // one bf16x8 fragment-lane per thread
    if (g >= KSTEPS * 32 * 64) return;
    int lane = g & 63;
    int a16  = (g >> 6) & 31;
    int ks   = g >> 11;
    int col = lane & 15, quad = lane >> 4;
    int a  = a16 * 16 + col;
    int d0 = ks * 32 + quad * 8;
    bf16x8 o;
    #pragma unroll
    for (int j = 0; j < 8; ++j) {
        int d = d0 + j;
        o[j] = (d < ND) ? (__bf16)w1[d * NA + a] : (__bf16)0.0f;
    }
    *(bf16x8*)(w1p + (size_t)g * 8) = o;
}

// ---------------- kernel 1: scores[b,t] = sum_a relu(sum_d w1[d,a] X[b,d,t] + b1[a]) * w2[a] ----
// One block per (t-tile, b). Each wave owns 128 a-rows x all 64 t (no cross-wave A duplication).
// A-frags: coalesced 1KB/wave loads from fragment-packed w1p (L2-resident), issued pre-barrier.
// Bs: pair-packed bf16 dwords, stride 17, double-buffered.
__global__ __launch_bounds__(256, 2) void score_kernel(
    const float* __restrict__ X,         // [B, D, T] fp32
    const __bf16* __restrict__ w1p,      // fragment-packed, see w1p_kernel
    const float* __restrict__ b1,
    const float* __restrict__ w2,
    float* __restrict__ scores)          // [B, T] fp32
{
    __shared__ unsigned Bs[2][64 * STR];  // [t][k/2] pair-packed bf16, double-buffered
    __shared__ float b1s[NA], w2s[NA];
    __shared__ float ssc[64];

    const int tt = blockIdx.x;
    const int b  = blockIdx.y;
    const int t0 = tt * 64;
    const int tid = threadIdx.x;

    for (int i = tid; i < NA; i += 256) { b1s[i] = b1[i]; w2s[i] = w2[i]; }

    const int lane = tid & 63;
    const int wave = tid >> 6;            // wave owns a in [wave*128, wave*128+128)
    const int col = lane & 15;
    const int quad = lane >> 4;

    // X staging map: thread handles d-pair (2*dr2, 2*dr2+1), 4 consecutive t
    const int dr2  = tid >> 4;            // 0..15
    const int toff = (tid & 15) << 2;     // 0..60
    const float* xbase = X + (size_t)b * (ND * NT) + (t0 + toff);
    const bool tval = (t0 + toff) < NT;   // T=1000, toff%4==0 -> whole-float4 guard

    // per-lane base into packed w1: a16 = wave*8 + u
    const __bf16* wlane = w1p + (size_t)(wave * 8) * 512 + (size_t)lane * 8;

    f32x4 acc[8][4];
    #pragma unroll
    for (int u = 0; u < 8; ++u)
        #pragma unroll
        for (int i = 0; i < 4; ++i)
            acc[u][i] = (f32x4){0.f, 0.f, 0.f, 0.f};

    // preload k=0 X tile and stage into Bs[0]
    {
        float4 g0 = {0,0,0,0}, g1 = {0,0,0,0};
        int d0 = 2 * dr2, d1 = d0 + 1;
        if (tval && d0 < ND) g0 = *(const float4*)(xbase + (size_t)d0 * NT);
        if (tval && d1 < ND) g1 = *(const float4*)(xbase + (size_t)d1 * NT);
        Bs[0][(toff + 0) * STR + dr2] = pack2(g0.x, g1.x);
        Bs[0][(toff + 1) * STR + dr2] = pack2(g0.y, g1.y);
        Bs[0][(toff + 2) * STR + dr2] = pack2(g0.z, g1.z);
        Bs[0][(toff + 3) * STR + dr2] = pack2(g0.w, g1.w);
    }

    for (int ks = 0; ks < KSTEPS; ++ks) {
        const int k0 = ks * 32;
        const int cur = ks & 1, nxt = cur ^ 1;

        // issue next k-tile's global X loads first (deepest latency)
        float4 n0 = {0,0,0,0}, n1 = {0,0,0,0};
        {
            int d0 = k0 + 32 + 2 * dr2, d1 = d0 + 1;
            if (tval && d0 < ND) n0 = *(const float4*)(xbase + (size_t)d0 * NT);
            if (tval && d1 < ND) n1 = *(const float4*)(xbase + (size_t)d1 * NT);
        }

        // A-frags for this k-step: coalesced L2 loads, issued BEFORE the barrier
        // so their latency hides under the sync wait.
        bf16x8 af[8];
        const __bf16* wk = wlane + (size_t)ks * (32 * 64 * 8);
        #pragma unroll
        for (int u = 0; u < 8; ++u)
            af[u] = *(const bf16x8*)(wk + (size_t)u * 512);

        __syncthreads();   // Bs[cur] writes from previous step visible

        // B-frags: all 4 t-frags of this t-tile (each reused by 8 a-chunks)
        bf16x8 bq[4];
        #pragma unroll
        for (int i = 0; i < 4; ++i) {
            int tl = i * 16 + col;
            BQ q;
            #pragma unroll
            for (int jp = 0; jp < 4; ++jp)
                q.u[jp] = Bs[cur][tl * STR + quad * 4 + jp];
            bq[i] = q.v;
        }

        #pragma unroll
        for (int u = 0; u < 8; ++u)
            #pragma unroll
            for (int i = 0; i < 4; ++i)
                acc[u][i] = __builtin_amdgcn_mfma_f32_16x16x32_bf16(af[u], bq[i], acc[u][i], 0, 0, 0);

        // stage next k-tile (other buffer, no race; visible after next barrier)
        Bs[nxt][(toff + 0) * STR + dr2] = pack2(n0.x, n1.x);
        Bs[nxt][(toff + 1) * STR + dr2] = pack2(n0.y, n1.y);
        Bs[nxt][(toff + 2) * STR + dr2] = pack2(n0.z, n1.z);
        Bs[nxt][(toff + 3) * STR + dr2] = pack2(n0.w, n1.w);
    }

    // ---------------- epilogue: full a-sum of relu(h+b1)*w2 per t ----------------
    float part[4] = {0.f, 0.f, 0.f, 0.f};
    #pragma unroll
    for (int u = 0; u < 8; ++u)
        #pragma unroll
        for (int r = 0; r < 4; ++r) {
            int a = wave * 128 + u * 16 + quad * 4 + r;
            float bb = b1s[a], ww = w2s[a];
            #pragma unroll
            for (int i = 0; i < 4; ++i) {
                float h = acc[u][i][r] + bb;
                part[i] += fmaxf(h, 0.f) * ww;
            }
        }

    __syncthreads();
    if (tid < 64) ssc[tid] = 0.f;
    __syncthreads();
    #pragma unroll
    for (int i = 0; i < 4; ++i) {
        float p = part[i];
        p += __shfl_down(p, 32);   // quad 2,3 -> 0,1
        p += __shfl_down(p, 16);   // quad 1 -> 0
        if (quad == 0) atomicAdd(&ssc[i * 16 + col], p);
    }
    __syncthreads();
    if (tid < 64) {
        int t = t0 + tid;
        if (t < NT) scores[b * NT + t] = ssc[tid];
    }
}

// ---------------- kernel 2: softmax over t, write A fp32 into d_out ----------------
__global__ __launch_bounds__(256) void softmax_kernel(
    const float* __restrict__ scores, float* __restrict__ A_out)
{
    __shared__ float red[256];
    const int b = blockIdx.x, tid = threadIdx.x;
    const float* s = scores + b * NT;
    float v[4], m = -1e30f;
    #pragma unroll
    for (int i = 0; i < 4; ++i) {
        int t = tid + i * 256;
        v[i] = (t < NT) ? s[t] : -1e30f;
        m = fmaxf(m, v[i]);
    }
    red[tid] = m; __syncthreads();
    for (int off = 128; off > 0; off >>= 1) {
        if (tid < off) red[tid] = fmaxf(red[tid], red[tid + off]);
        __syncthreads();
    }
    m = red[0]; __syncthreads();
    float sum = 0.f;
    #pragma unroll
    for (int i = 0; i < 4; ++i) {
        v[i] = __expf(v[i] - m);
        if (tid + i * 256 < NT) sum += v[i]; else v[i] = 0.f;
    }
    red[tid] = sum; __syncthreads();
    for (int off = 128; off > 0; off >>= 1) {
        if (tid < off) red[tid] += red[tid + off];
        __syncthreads();
    }
    float inv = 1.f / red[0];
    #pragma unroll
    for (int i = 0; i < 4; ++i) {
        int t = tid + i * 256;
        if (t < NT) A_out[b * NT + t] = v[i] * inv;
    }
}

// ---------------- kernel 3: E, std pooling. wave per d-row, coalesced over t ----------------
__global__ __launch_bounds__(256) void pool_kernel(
    const float* __restrict__ X, const float* __restrict__ A,   // A = d_out[0:NB*NT]
    float* __restrict__ outE)                                   // d_out + NB*NT
{
    __shared__ float As[NT];
    const int b = blockIdx.x;
    const int d0 = blockIdx.y << 2;
    const int tid = threadIdx.x;
    for (int t = tid; t < NT; t += 256) As[t] = A[b * NT + t];
    __syncthreads();
    const int wave = tid >> 6, lane = tid & 63;
    const int d = d0 + wave;
    const float* x = X + (size_t)b * (ND * NT) + (size_t)d * NT;
    float e = 0.f, q = 0.f;
    #pragma unroll
    for (int it = 0; it < 4; ++it) {
        int t = it * 256 + (lane << 2);
        if (t < NT) {                                  // 1000 % 4 == 0 -> whole-vector guard
            float4 xv = *(const float4*)(x + t);
            float4 a4 = *(const float4*)(As + t);
            e += xv.x * a4.x + xv.y * a4.y + xv.z * a4.z + xv.w * a4.w;
            q += xv.x * xv.x * a4.x + xv.y * xv.y * a4.y + xv.z * xv.z * a4.z + xv.w * xv.w * a4.w;
        }
    }
    #pragma unroll
    for (int off = 32; off > 0; off >>= 1) {
        e += __shfl_down(e, off);
        q += __shfl_down(q, off);
    }
    if (lane == 0) {
        outE[b * 3000 + d] = e;
        outE[b * 3000 + 1500 + d] = sqrtf(fmaxf(q - e * e, 0.f) + 1e-5f);
    }
}

extern "C" void kernel_launch(void* const* d_in, const int* in_sizes, int n_in,
                              void* d_out, int out_size, void* d_ws, size_t ws_size,
                              hipStream_t stream) {
    const float* X  = (const float*)d_in[0];
    const float* w1 = (const float*)d_in[1];
    const float* b1 = (const float*)d_in[2];
    const float* w2 = (const float*)d_in[3];
    // d_in[4] = bias_2: scalar added to every t -> cancels in softmax over t; outputs unaffected.

    char* ws = (char*)d_ws;
    __bf16* w1p    = (__bf16*)ws;                                  // 47*32*64*8*2 = 1,540,096 B
    float*  scores = (float*)(ws + (size_t)KSTEPS * 32 * 64 * 8 * 2); // NB*NT*4 = 256,000 B

    float* out = (float*)d_out;                          // [A : NB*NT][layer_out : NB*3000]

    w1p_kernel<<<(KSTEPS * 32 * 64 + 255) / 256, 256, 0, stream>>>(w1, w1p);
    score_kernel<<<dim3(16, NB), 256, 0, stream>>>(X, w1p, b1, w2, scores);
    softmax_kernel<<<NB, 256, 0, stream>>>(scores, out);
    pool_kernel<<<dim3(NB, ND / 4), 256, 0, stream>>>(X, out, out + NB * NT);
}

// Round 2
// 629.067 us; speedup vs baseline: 1.3240x; 1.0540x over previous
//
#include <hip/hip_runtime.h>
#include <hip/hip_bf16.h>

#define NB 64
#define ND 1500
#define NT 1000
#define NA 512
#define KSTEPS 47   // ceil(1500/32)
#define STR 17      // Bs t-stride in dwords (16 k-pair dwords + 1 pad)

typedef __bf16 bf16x8 __attribute__((ext_vector_type(8)));
typedef float  f32x4  __attribute__((ext_vector_type(4)));

union BQ { unsigned u[4]; bf16x8 v; };

static __device__ __forceinline__ unsigned pack2(float lo, float hi) {
    __bf16 l = (__bf16)lo, h = (__bf16)hi;
    unsigned short lu = __builtin_bit_cast(unsigned short, l);
    unsigned short hu = __builtin_bit_cast(unsigned short, h);
    return ((unsigned)hu << 16) | (unsigned)lu;
}

// ---------------- kernel 0: pack w1 [D,NA] fp32 -> MFMA-fragment-ordered bf16 ----------------
// Layout: elem offset = ((ks*32 + a16)*64 + lane)*8, lane=(quad<<4)|col holds
// A[a = a16*16+col][k = ks*32 + quad*8 + j], j=0..7 (zero-padded for d >= ND).
__global__ void w1p_kernel(const float* __restrict__ w1, __bf16* __restrict__ w1p) {
    int g = blockIdx.x * 256 + threadIdx.x;       // one bf16x8 fragment-lane per thread
    if (g >= KSTEPS * 32 * 64) return;
    int lane = g & 63;
    int a16  = (g >> 6) & 31;
    int ks   = g >> 11;
    int col = lane & 15, quad = lane >> 4;
    int a  = a16 * 16 + col;
    int d0 = ks * 32 + quad * 8;
    bf16x8 o;
    #pragma unroll
    for (int j = 0; j < 8; ++j) {
        int d = d0 + j;
        o[j] = (d < ND) ? (__bf16)w1[d * NA + a] : (__bf16)0.0f;
    }
    *(bf16x8*)(w1p + (size_t)g * 8) = o;
}

// ---------------- kernel 1: scores[b,t] = sum_a relu(sum_d w1[d,a] X[b,d,t] + b1[a]) * w2[a] ----
// One block per (t-tile, b). Each wave owns 128 a-rows x all 64 t.
// Raw s_barrier with lgkmcnt-only drain: X (HBM) and A-frag (L2) loads stay in
// flight across the barrier (the __syncthreads vmcnt(0) drain was ~5.7K cyc/step).
// X pipelined 2 steps deep: tile ks+2 issued during step ks, written end of step ks+1.
__global__ __launch_bounds__(256, 2) void score_kernel(
    const float* __restrict__ X,         // [B, D, T] fp32
    const __bf16* __restrict__ w1p,      // fragment-packed, see w1p_kernel
    const float* __restrict__ b1,
    const float* __restrict__ w2,
    float* __restrict__ scores)          // [B, T] fp32
{
    __shared__ unsigned Bs[2][64 * STR];  // [t][k/2] pair-packed bf16, double-buffered
    __shared__ float b1s[NA], w2s[NA];
    __shared__ float ssc[64];

    const int tt = blockIdx.x;
    const int b  = blockIdx.y;
    const int t0 = tt * 64;
    const int tid = threadIdx.x;

    for (int i = tid; i < NA; i += 256) { b1s[i] = b1[i]; w2s[i] = w2[i]; }

    const int lane = tid & 63;
    const int wave = tid >> 6;            // wave owns a in [wave*128, wave*128+128)
    const int col = lane & 15;
    const int quad = lane >> 4;

    // X staging map: thread handles d-pair (2*dr2, 2*dr2+1), 4 consecutive t
    const int dr2  = tid >> 4;            // 0..15
    const int toff = (tid & 15) << 2;     // 0..60
    const float* xbase = X + (size_t)b * (ND * NT) + (t0 + toff);
    const bool tval = (t0 + toff) < NT;   // T=1000, toff%4==0 -> whole-float4 guard

    // per-lane base into packed w1: a16 = wave*8 + u
    const __bf16* wlane = w1p + (size_t)(wave * 8) * 512 + (size_t)lane * 8;

    f32x4 acc[8][4];
    #pragma unroll
    for (int u = 0; u < 8; ++u)
        #pragma unroll
        for (int i = 0; i < 4; ++i)
            acc[u][i] = (f32x4){0.f, 0.f, 0.f, 0.f};

    // ---- prologue: stage tile 0 into Bs[0]; preload Xc = tile 1 into regs ----
    {
        float4 g0 = {0,0,0,0}, g1 = {0,0,0,0};
        int d0 = 2 * dr2, d1 = d0 + 1;
        if (tval && d0 < ND) g0 = *(const float4*)(xbase + (size_t)d0 * NT);
        if (tval && d1 < ND) g1 = *(const float4*)(xbase + (size_t)d1 * NT);
        Bs[0][(toff + 0) * STR + dr2] = pack2(g0.x, g1.x);
        Bs[0][(toff + 1) * STR + dr2] = pack2(g0.y, g1.y);
        Bs[0][(toff + 2) * STR + dr2] = pack2(g0.z, g1.z);
        Bs[0][(toff + 3) * STR + dr2] = pack2(g0.w, g1.w);
    }
    float4 c0 = {0,0,0,0}, c1 = {0,0,0,0};   // X regs for tile ks+1 (written end of step ks)
    {
        int d0 = 32 + 2 * dr2, d1 = d0 + 1;
        if (tval && d0 < ND) c0 = *(const float4*)(xbase + (size_t)d0 * NT);
        if (tval && d1 < ND) c1 = *(const float4*)(xbase + (size_t)d1 * NT);
    }

    for (int ks = 0; ks < KSTEPS; ++ks) {
        const int cur = ks & 1;

        // A-frags for THIS step: issued first so the MFMA's vmcnt wait is
        // vmcnt(2) (X still in flight), not a full drain. L2-resident, coalesced.
        bf16x8 af[8];
        const __bf16* wk = wlane + (size_t)ks * (32 * 64 * 8);
        #pragma unroll
        for (int u = 0; u < 8; ++u)
            af[u] = *(const bf16x8*)(wk + (size_t)u * 512);

        // X loads for tile ks+2 (consumed end of NEXT step -> ~2 steps to land)
        float4 n0 = {0,0,0,0}, n1 = {0,0,0,0};
        {
            int d0 = ks * 32 + 64 + 2 * dr2, d1 = d0 + 1;
            if (tval && d0 < ND) n0 = *(const float4*)(xbase + (size_t)d0 * NT);
            if (tval && d1 < ND) n1 = *(const float4*)(xbase + (size_t)d1 * NT);
        }

        // barrier with LDS-only drain: my prev-step ds_writes visible, vmem stays in flight
        asm volatile("s_waitcnt lgkmcnt(0)" ::: "memory");
        __builtin_amdgcn_s_barrier();

        // B-frags: all 4 t-frags of this t-tile (each reused by 8 a-chunks)
        bf16x8 bq[4];
        #pragma unroll
        for (int i = 0; i < 4; ++i) {
            int tl = i * 16 + col;
            BQ q;
            #pragma unroll
            for (int jp = 0; jp < 4; ++jp)
                q.u[jp] = Bs[cur][tl * STR + quad * 4 + jp];
            bq[i] = q.v;
        }

        #pragma unroll
        for (int u = 0; u < 8; ++u)
            #pragma unroll
            for (int i = 0; i < 4; ++i)
                acc[u][i] = __builtin_amdgcn_mfma_f32_16x16x32_bf16(af[u], bq[i], acc[u][i], 0, 0, 0);

        // write tile ks+1 (regs loaded during step ks-1; latency fully covered)
        Bs[cur ^ 1][(toff + 0) * STR + dr2] = pack2(c0.x, c1.x);
        Bs[cur ^ 1][(toff + 1) * STR + dr2] = pack2(c0.y, c1.y);
        Bs[cur ^ 1][(toff + 2) * STR + dr2] = pack2(c0.z, c1.z);
        Bs[cur ^ 1][(toff + 3) * STR + dr2] = pack2(c0.w, c1.w);

        c0 = n0; c1 = n1;
    }

    // ---------------- epilogue: full a-sum of relu(h+b1)*w2 per t ----------------
    float part[4] = {0.f, 0.f, 0.f, 0.f};
    #pragma unroll
    for (int u = 0; u < 8; ++u)
        #pragma unroll
        for (int r = 0; r < 4; ++r) {
            int a = wave * 128 + u * 16 + quad * 4 + r;
            float bb = b1s[a], ww = w2s[a];
            #pragma unroll
            for (int i = 0; i < 4; ++i) {
                float h = acc[u][i][r] + bb;
                part[i] += fmaxf(h, 0.f) * ww;
            }
        }

    __syncthreads();
    if (tid < 64) ssc[tid] = 0.f;
    __syncthreads();
    #pragma unroll
    for (int i = 0; i < 4; ++i) {
        float p = part[i];
        p += __shfl_down(p, 32);   // quad 2,3 -> 0,1
        p += __shfl_down(p, 16);   // quad 1 -> 0
        if (quad == 0) atomicAdd(&ssc[i * 16 + col], p);
    }
    __syncthreads();
    if (tid < 64) {
        int t = t0 + tid;
        if (t < NT) scores[b * NT + t] = ssc[tid];
    }
}

// ---------------- kernel 2: softmax over t, write A fp32 into d_out ----------------
__global__ __launch_bounds__(256) void softmax_kernel(
    const float* __restrict__ scores, float* __restrict__ A_out)
{
    __shared__ float red[256];
    const int b = blockIdx.x, tid = threadIdx.x;
    const float* s = scores + b * NT;
    float v[4], m = -1e30f;
    #pragma unroll
    for (int i = 0; i < 4; ++i) {
        int t = tid + i * 256;
        v[i] = (t < NT) ? s[t] : -1e30f;
        m = fmaxf(m, v[i]);
    }
    red[tid] = m; __syncthreads();
    for (int off = 128; off > 0; off >>= 1) {
        if (tid < off) red[tid] = fmaxf(red[tid], red[tid + off]);
        __syncthreads();
    }
    m = red[0]; __syncthreads();
    float sum = 0.f;
    #pragma unroll
    for (int i = 0; i < 4; ++i) {
        v[i] = __expf(v[i] - m);
        if (tid + i * 256 < NT) sum += v[i]; else v[i] = 0.f;
    }
    red[tid] = sum; __syncthreads();
    for (int off = 128; off > 0; off >>= 1) {
        if (tid < off) red[tid] += red[tid + off];
        __syncthreads();
    }
    float inv = 1.f / red[0];
    #pragma unroll
    for (int i = 0; i < 4; ++i) {
        int t = tid + i * 256;
        if (t < NT) A_out[b * NT + t] = v[i] * inv;
    }
}

// ---------------- kernel 3: E, std pooling. wave per d-row, coalesced over t ----------------
__global__ __launch_bounds__(256) void pool_kernel(
    const float* __restrict__ X, const float* __restrict__ A,   // A = d_out[0:NB*NT]
    float* __restrict__ outE)                                   // d_out + NB*NT
{
    __shared__ float As[NT];
    const int b = blockIdx.x;
    const int d0 = blockIdx.y << 2;
    const int tid = threadIdx.x;
    for (int t = tid; t < NT; t += 256) As[t] = A[b * NT + t];
    __syncthreads();
    const int wave = tid >> 6, lane = tid & 63;
    const int d = d0 + wave;
    const float* x = X + (size_t)b * (ND * NT) + (size_t)d * NT;
    float e = 0.f, q = 0.f;
    #pragma unroll
    for (int it = 0; it < 4; ++it) {
        int t = it * 256 + (lane << 2);
        if (t < NT) {                                  // 1000 % 4 == 0 -> whole-vector guard
            float4 xv = *(const float4*)(x + t);
            float4 a4 = *(const float4*)(As + t);
            e += xv.x * a4.x + xv.y * a4.y + xv.z * a4.z + xv.w * a4.w;
            q += xv.x * xv.x * a4.x + xv.y * xv.y * a4.y + xv.z * xv.z * a4.z + xv.w * xv.w * a4.w;
        }
    }
    #pragma unroll
    for (int off = 32; off > 0; off >>= 1) {
        e += __shfl_down(e, off);
        q += __shfl_down(q, off);
    }
    if (lane == 0) {
        outE[b * 3000 + d] = e;
        outE[b * 3000 + 1500 + d] = sqrtf(fmaxf(q - e * e, 0.f) + 1e-5f);
    }
}

extern "C" void kernel_launch(void* const* d_in, const int* in_sizes, int n_in,
                              void* d_out, int out_size, void* d_ws, size_t ws_size,
                              hipStream_t stream) {
    const float* X  = (const float*)d_in[0];
    const float* w1 = (const float*)d_in[1];
    const float* b1 = (const float*)d_in[2];
    const float* w2 = (const float*)d_in[3];
    // d_in[4] = bias_2: scalar added to every t -> cancels in softmax over t; outputs unaffected.

    char* ws = (char*)d_ws;
    __bf16* w1p    = (__bf16*)ws;                                     // 47*32*64*8*2 = 1,540,096 B
    float*  scores = (float*)(ws + (size_t)KSTEPS * 32 * 64 * 8 * 2); // NB*NT*4 = 256,000 B

    float* out = (float*)d_out;                          // [A : NB*NT][layer_out : NB*3000]

    w1p_kernel<<<(KSTEPS * 32 * 64 + 255) / 256, 256, 0, stream>>>(w1, w1p);
    score_kernel<<<dim3(16, NB), 256, 0, stream>>>(X, w1p, b1, w2, scores);
    softmax_kernel<<<NB, 256, 0, stream>>>(scores, out);
    pool_kernel<<<dim3(NB, ND / 4), 256, 0, stream>>>(X, out, out + NB * NT);
}